// Round 3
// baseline (59.669 us; speedup 1.0000x reference)
//
#include <hip/hip_runtime.h>
#include <math.h>

#define S_   2048
#define D_   1024
#define K0   8
#define LNEPS 1e-5f

typedef __attribute__((ext_vector_type(8)))  __bf16 bf16x8;
typedef __attribute__((ext_vector_type(16))) float  floatx16;

__device__ __forceinline__ unsigned short bf16_rne(float v) {
    unsigned u = __float_as_uint(v);
    u += 0x7FFFu + ((u >> 16) & 1u);
    return (unsigned short)(u >> 16);
}
__device__ __forceinline__ float bf16_tof(unsigned short h) {
    return __uint_as_float(((unsigned)h) << 16);
}

// =========================================================================
// Kernel 1: split Wg (f32 -> bf16 hi/lo planes), gather+split x rows for the
// 16 needed token slots, and compute A-means.  grid = 2048 + 512 + 2.
// =========================================================================
__global__ __launch_bounds__(256)
void k_split(const int* __restrict__ ids, const float* __restrict__ emb,
             const float* __restrict__ Wg_f, const float* __restrict__ Wg_b,
             const float* __restrict__ A_f, const float* __restrict__ A_b,
             unsigned short* __restrict__ wg_hi, unsigned short* __restrict__ wg_lo,
             unsigned short* __restrict__ xs_hi, unsigned short* __restrict__ xs_lo,
             float* __restrict__ a_ws)
{
    __shared__ float red[256 * 16];
    const int bid = blockIdx.x, tid = threadIdx.x;

    if (bid < 2560) {
        const float* src;
        unsigned short *dh, *dl;
        if (bid < 2048) {                      // Wg rows: bid = dir*1024 + e
            const int dir = bid >> 10, e = bid & 1023;
            src = (dir ? Wg_b : Wg_f) + (size_t)e * D_;
            dh = wg_hi + (size_t)bid * D_;
            dl = wg_lo + (size_t)bid * D_;
        } else {                               // x rows: r = t*32 + b
            const int r = bid - 2048;
            const int t = r >> 5, b = r & 31;
            const int dir = t >> 3, step = t & 7;
            const int pos = dir ? (K0 - 1 - step) : (S_ - K0 + step);
            const int tok = ids[b * S_ + pos];
            src = emb + (size_t)tok * D_;
            dh = xs_hi + (size_t)r * D_;
            dl = xs_lo + (size_t)r * D_;
        }
        const float4 v = *(const float4*)(src + tid * 4);
        ushort4 h, l;
        h.x = bf16_rne(v.x); l.x = bf16_rne(v.x - bf16_tof(h.x));
        h.y = bf16_rne(v.y); l.y = bf16_rne(v.y - bf16_tof(h.y));
        h.z = bf16_rne(v.z); l.z = bf16_rne(v.z - bf16_tof(h.z));
        h.w = bf16_rne(v.w); l.w = bf16_rne(v.w - bf16_tof(h.w));
        *(ushort4*)(dh + tid * 4) = h;
        *(ushort4*)(dl + tid * 4) = l;
        return;
    }

    // A-mean blocks (2): a_ws[dir*16+n] = mean_d A[d][n]
    const int dir = bid - 2560;
    const float* __restrict__ A = dir ? A_b : A_f;
    float4 s0 = {0,0,0,0}, s1 = s0, s2 = s0, s3 = s0;
    for (int r = tid; r < 1024; r += 256) {
        const float4* row = (const float4*)(A + r * 16);
        float4 a0 = row[0], a1 = row[1], a2 = row[2], a3 = row[3];
        s0.x += a0.x; s0.y += a0.y; s0.z += a0.z; s0.w += a0.w;
        s1.x += a1.x; s1.y += a1.y; s1.z += a1.z; s1.w += a1.w;
        s2.x += a2.x; s2.y += a2.y; s2.z += a2.z; s2.w += a2.w;
        s3.x += a3.x; s3.y += a3.y; s3.z += a3.z; s3.w += a3.w;
    }
    float* my = red + tid * 16;
    ((float4*)my)[0] = s0; ((float4*)my)[1] = s1;
    ((float4*)my)[2] = s2; ((float4*)my)[3] = s3;
    __syncthreads();
    for (int st = 128; st > 0; st >>= 1) {
        if (tid < st) {
            const float* other = red + (tid + st) * 16;
#pragma unroll
            for (int i = 0; i < 16; ++i) my[i] += other[i];
        }
        __syncthreads();
    }
    if (tid < 16) a_ws[dir * 16 + tid] = red[tid] * (1.f / 1024.f);
}

// =========================================================================
// Kernel 2: MFMA gate GEMM (Dekker bf16x2, 3 MFMA per K=16) + fused
// sigmoid-gate + WB projection -> bt_part[t][et][b][n].
// grid = 512 one-wave blocks; id swizzled so each XCD holds one direction.
// Wave tile: 32e x 32b x K=1024.  No LDS.
// =========================================================================
__global__ __launch_bounds__(64)
void k_gate(const int* __restrict__ ids, const float* __restrict__ emb,
            const float* __restrict__ bg_f, const float* __restrict__ bg_b,
            const float* __restrict__ WB_f, const float* __restrict__ WB_b,
            const unsigned short* __restrict__ wg_hi,
            const unsigned short* __restrict__ wg_lo,
            const unsigned short* __restrict__ xs_hi,
            const unsigned short* __restrict__ xs_lo,
            float* __restrict__ bt_part)
{
    const int id   = blockIdx.x;
    const int dir  = id & 1;                  // XCD parity -> one dir per XCD L2
    const int step = (id >> 1) & 7;
    const int et   = id >> 4;                 // 0..31
    const int t    = dir * 8 + step;
    const int e0   = et * 32;

    const int lane = threadIdx.x;
    const int row  = lane & 31;               // A: e-row ; B: b-col
    const int kb   = lane >> 5;               // k-block (0/1) within frag

    const size_t abase = ((size_t)(dir * D_ + e0 + row)) * D_ + kb * 8;
    const size_t bbase = ((size_t)(t * 32 + row)) * D_ + kb * 8;

    floatx16 acc;
#pragma unroll
    for (int i = 0; i < 16; ++i) acc[i] = 0.f;

    for (int k0 = 0; k0 < D_; k0 += 16) {
        const bf16x8 ah = *(const bf16x8*)(wg_hi + abase + k0);
        const bf16x8 al = *(const bf16x8*)(wg_lo + abase + k0);
        const bf16x8 bh = *(const bf16x8*)(xs_hi + bbase + k0);
        const bf16x8 bl = *(const bf16x8*)(xs_lo + bbase + k0);
        acc = __builtin_amdgcn_mfma_f32_32x32x16_bf16(ah, bh, acc, 0, 0, 0);
        acc = __builtin_amdgcn_mfma_f32_32x32x16_bf16(ah, bl, acc, 0, 0, 0);
        acc = __builtin_amdgcn_mfma_f32_32x32x16_bf16(al, bh, acc, 0, 0, 0);
    }

    // epilogue: lane holds y[e0+er][b=row] for er=(r&3)+8*(r>>2)+4*kb
    const float* __restrict__ bgv = dir ? bg_b : bg_f;
    const float* __restrict__ WB  = dir ? WB_b : WB_f;
    const int pos = dir ? (K0 - 1 - step) : (S_ - K0 + step);
    const int tok = ids[row * S_ + pos];
    const int hi4 = kb * 4;

    float xg[16];
#pragma unroll
    for (int r = 0; r < 16; ++r) {
        const int e = e0 + (r & 3) + 8 * (r >> 2) + hi4;
        const float y = acc[r] + bgv[e];
        const float g = 1.f / (1.f + __expf(-y));
        xg[r] = g * emb[(size_t)tok * D_ + e];
    }

    float btp[16];
#pragma unroll
    for (int n = 0; n < 16; ++n) {
        float s = 0.f;
#pragma unroll
        for (int q = 0; q < 4; ++q) {
            const float4 w = *(const float4*)(WB + n * D_ + e0 + 8 * q + hi4);
            s += w.x * xg[4*q] + w.y * xg[4*q+1] + w.z * xg[4*q+2] + w.w * xg[4*q+3];
        }
        s += __shfl_xor(s, 32, 64);           // fold kb halves (same b)
        btp[n] = s;
    }
    if (lane < 32) {
        float* dst = bt_part + (((size_t)t * 32 + et) * 32 + row) * 16;
#pragma unroll
        for (int i = 0; i < 4; ++i)
            *(float4*)(dst + 4 * i) = make_float4(btp[4*i], btp[4*i+1],
                                                  btp[4*i+2], btp[4*i+3]);
    }
}

// =========================================================================
__device__ __forceinline__ float block_sum(float v, float* r4, int tid)
{
#pragma unroll
    for (int m = 32; m >= 1; m >>= 1) v += __shfl_xor(v, m, 64);
    if ((tid & 63) == 0) r4[tid >> 6] = v;
    __syncthreads();
    const float r = r4[0] + r4[1] + r4[2] + r4[3];
    __syncthreads();
    return r;
}

// =========================================================================
// Kernel 3: reduce bt_part over etiles, recurrence, z1 = hc@W1^T, LN, ReLU.
// grid = 32 (batch), block = 256.
// =========================================================================
__global__ __launch_bounds__(256)
void k_recur_ln(const float* __restrict__ a_ws, const float* __restrict__ bt_part,
                const float* __restrict__ W1, const float* __restrict__ b1,
                const float* __restrict__ ln_g, const float* __restrict__ ln_b,
                float* __restrict__ z_ws)
{
    const int b = blockIdx.x, tid = threadIdx.x;
    __shared__ float Bt_s[256];               // [t][n]
    __shared__ float hc_s[32];
    __shared__ float r4[4];

    {   // sum 32 etile partials for (t = tid>>4, n = tid&15)
        const int t = tid >> 4, n = tid & 15;
        const float* p = bt_part + (size_t)t * 16384 + b * 16 + n;
        float s = 0.f;
#pragma unroll
        for (int et = 0; et < 32; ++et) s += p[et * 512];
        Bt_s[tid] = s;
    }
    __syncthreads();

    if (tid < 32) {
        const float a = a_ws[tid];
        const int dirv = tid >> 4, n = tid & 15;
        float h = 0.f;
#pragma unroll
        for (int j = 0; j < K0; ++j)
            h = tanhf(h * a + Bt_s[(dirv * 8 + j) * 16 + n]);
        hc_s[tid] = h;
    }
    __syncthreads();

    float z1[4];
    float s1 = 0.f, s2 = 0.f;
    const int e0 = tid * 4;
#pragma unroll
    for (int c = 0; c < 4; ++c) {
        const int e = e0 + c;
        float acc = b1[e];
        const float* w = W1 + e * 32;
#pragma unroll
        for (int i = 0; i < 32; ++i) acc += hc_s[i] * w[i];
        z1[c] = acc; s1 += acc; s2 += acc * acc;
    }
    s1 = block_sum(s1, r4, tid);
    s2 = block_sum(s2, r4, tid);
    const float mu  = s1 * (1.f / 1024.f);
    const float var = s2 * (1.f / 1024.f) - mu * mu;
    const float inv = 1.0f / sqrtf(var + LNEPS);

    float4 ov;
    float* o = (float*)&ov;
#pragma unroll
    for (int c = 0; c < 4; ++c) {
        const int e = e0 + c;
        const float zc = (z1[c] - mu) * inv * ln_g[e] + ln_b[e];
        o[c] = fmaxf(zc, 0.f);
    }
    *(float4*)(z_ws + b * 1024 + e0) = ov;
}

// =========================================================================
// Kernel 4: z2[b][f] = relu(W2[f]·z[b] + b2[f]).  grid = 256 (2 f each).
// =========================================================================
__global__ __launch_bounds__(256)
void k_w2(const float* __restrict__ W2, const float* __restrict__ b2,
          const float* __restrict__ z_ws, float* __restrict__ z2_ws)
{
    const int f0 = blockIdx.x * 2;
    const int tid = threadIdx.x;
    const float4 w0 = *(const float4*)(W2 + (size_t)f0 * D_ + tid * 4);
    const float4 w1 = *(const float4*)(W2 + (size_t)(f0 + 1) * D_ + tid * 4);
    float a0[32], a1[32];
#pragma unroll
    for (int b = 0; b < 32; ++b) {
        const float4 z = *(const float4*)(z_ws + b * D_ + tid * 4);
        a0[b] = w0.x * z.x + w0.y * z.y + w0.z * z.z + w0.w * z.w;
        a1[b] = w1.x * z.x + w1.y * z.y + w1.z * z.z + w1.w * z.w;
    }
    __shared__ float red[32 * 260];
    const int wv = tid >> 6, lane = tid & 63;

#pragma unroll
    for (int bq = 0; bq < 32; ++bq) red[bq * 260 + tid] = a0[bq];
    __syncthreads();
    {
        const float bias = b2[f0];
#pragma unroll
        for (int bi = 0; bi < 8; ++bi) {
            const int b = wv * 8 + bi;
            const float* rb = red + b * 260;
            float s = rb[lane] + rb[lane + 64] + rb[lane + 128] + rb[lane + 192];
#pragma unroll
            for (int m = 32; m >= 1; m >>= 1) s += __shfl_xor(s, m, 64);
            if (lane == 0) z2_ws[b * 512 + f0] = fmaxf(s + bias, 0.f);
        }
    }
    __syncthreads();
#pragma unroll
    for (int bq = 0; bq < 32; ++bq) red[bq * 260 + tid] = a1[bq];
    __syncthreads();
    {
        const float bias = b2[f0 + 1];
#pragma unroll
        for (int bi = 0; bi < 8; ++bi) {
            const int b = wv * 8 + bi;
            const float* rb = red + b * 260;
            float s = rb[lane] + rb[lane + 64] + rb[lane + 128] + rb[lane + 192];
#pragma unroll
            for (int m = 32; m >= 1; m >>= 1) s += __shfl_xor(s, m, 64);
            if (lane == 0) z2_ws[b * 512 + f0 + 1] = fmaxf(s + bias, 0.f);
        }
    }
}

// =========================================================================
// Kernel 5: out[b][o] = z2[b]·Wh[o] + bh[o].  grid = 32, block = 192.
// =========================================================================
__global__ __launch_bounds__(192)
void k_head(const float* __restrict__ Wh, const float* __restrict__ bh,
            const float* __restrict__ z2_ws, float* __restrict__ out)
{
    const int b = blockIdx.x;
    const int o = threadIdx.x >> 6, lane = threadIdx.x & 63;
    float s = 0.f;
#pragma unroll
    for (int j = 0; j < 2; ++j) {
        const float4 z = *(const float4*)(z2_ws + b * 512 + lane * 4 + j * 256);
        const float4 w = *(const float4*)(Wh + o * 512 + lane * 4 + j * 256);
        s += z.x * w.x + z.y * w.y + z.z * w.z + z.w * w.w;
    }
#pragma unroll
    for (int m = 32; m >= 1; m >>= 1) s += __shfl_xor(s, m, 64);
    if (lane == 0) out[b * 3 + o] = s + bh[o];
}

// =========================================================================
extern "C" void kernel_launch(void* const* d_in, const int* in_sizes, int n_in,
                              void* d_out, int out_size, void* d_ws, size_t ws_size,
                              hipStream_t stream)
{
    (void)in_sizes; (void)n_in; (void)out_size; (void)ws_size;

    const int*   ids  = (const int*)d_in[0];
    const float* emb  = (const float*)d_in[1];
    const float* A_f  = (const float*)d_in[2];
    const float* Wg_f = (const float*)d_in[3];
    const float* bg_f = (const float*)d_in[4];
    const float* WB_f = (const float*)d_in[5];
    const float* A_b  = (const float*)d_in[6];
    const float* Wg_b = (const float*)d_in[7];
    const float* bg_b = (const float*)d_in[8];
    const float* WB_b = (const float*)d_in[9];
    const float* W1   = (const float*)d_in[10];
    const float* b1   = (const float*)d_in[11];
    const float* ln_g = (const float*)d_in[12];
    const float* ln_b = (const float*)d_in[13];
    const float* W2   = (const float*)d_in[14];
    const float* b2   = (const float*)d_in[15];
    const float* Wh   = (const float*)d_in[16];
    const float* bh   = (const float*)d_in[17];

    float* W = (float*)d_ws;
    float* bt_part = W;                       // 16*32*32*16 = 262144 f (1 MB)
    float* a_ws    = W + 262144;              // 32 f
    float* z_ws    = W + 262176;              // 32768 f
    float* z2_ws   = W + 294944;              // 16384 f
    unsigned short* wg_hi = (unsigned short*)(W + 311328);   // 2M u16 (4 MB)
    unsigned short* wg_lo = wg_hi + 2097152;                 // 4 MB
    unsigned short* xs_hi = wg_lo + 2097152;                 // 512K u16 (1 MB)
    unsigned short* xs_lo = xs_hi + 524288;                  // 1 MB

    k_split<<<2562, 256, 0, stream>>>(ids, emb, Wg_f, Wg_b, A_f, A_b,
                                      wg_hi, wg_lo, xs_hi, xs_lo, a_ws);
    k_gate<<<512, 64, 0, stream>>>(ids, emb, bg_f, bg_b, WB_f, WB_b,
                                   wg_hi, wg_lo, xs_hi, xs_lo, bt_part);
    k_recur_ln<<<32, 256, 0, stream>>>(a_ws, bt_part, W1, b1, ln_g, ln_b, z_ws);
    k_w2<<<256, 256, 0, stream>>>(W2, b2, z_ws, z2_ws);
    k_head<<<32, 192, 0, stream>>>(Wh, bh, z2_ws, (float*)d_out);
}